// Round 2
// baseline (139.484 us; speedup 1.0000x reference)
//
#include <hip/hip_runtime.h>

#define E_ 15000
#define D_ 200
#define L_ 64
#define B_ 256
#define BT 8
#define LOG2E 1.4426950408889634f

// Precompute per-b gathered/transposed operands into workspace:
//   qt[d][b] = emb_e[e1[b],d] * emb_rel[rel[b],d]        (D_ x B_)
//   su[l][b] = (lit[e1[b],l] - c[l]) * sqrt(log2e/var[l]) (L_ x B_)
//   wt[l][b] = nf_weights[rel[b],l]                       (L_ x B_)
//   r[l]     = sqrt(log2e / var[l])
// so that phi = exp2( -(su - x*r)^2 ).
__global__ __launch_bounds__(256) void setup_k(
    const float* __restrict__ emb_e, const float* __restrict__ emb_rel,
    const float* __restrict__ nfw,   const float* __restrict__ lit,
    const float* __restrict__ c,     const float* __restrict__ var,
    const int* __restrict__ e1,      const int* __restrict__ rel,
    float* __restrict__ qt, float* __restrict__ su,
    float* __restrict__ wt, float* __restrict__ r)
{
    const int b = blockIdx.x;
    const int t = threadIdx.x;
    const int ie = e1[b];
    const int ir = rel[b];
    if (t < D_) qt[t * B_ + b] = emb_e[ie * D_ + t] * emb_rel[ir * D_ + t];
    if (t < L_) {
        const float rl = sqrtf(LOG2E / var[t]);
        su[t * B_ + b] = (lit[ie * L_ + t] - c[t]) * rl;
        wt[t * B_ + b] = nfw[ir * L_ + t];
        if (b == 0) r[t] = rl;
    }
}

// lane -> e (coalesced output), BT b's per block held in registers.
// Per-b operands (qt/su/wt/r) are wave-uniform -> scalar/broadcast loads.
__global__ __launch_bounds__(256) void main_k(
    const float* __restrict__ emb_e, const float* __restrict__ lit,
    const float* __restrict__ qt,    const float* __restrict__ su,
    const float* __restrict__ wt,    const float* __restrict__ r,
    float* __restrict__ out)
{
    const int e  = blockIdx.x * 256 + threadIdx.x;
    const int ec = (e < E_) ? e : (E_ - 1);   // clamp for loads; stores guarded
    const int b0 = blockIdx.y * BT;

    float acc[BT];
    #pragma unroll
    for (int i = 0; i < BT; ++i) acc[i] = 0.0f;

    // ---- structural score: acc[bb] += emb_e[ec,:] . qt[:, b0+bb] ----
    const float* ee = emb_e + (size_t)ec * D_;
    #pragma unroll 2
    for (int d = 0; d < D_; d += 4) {
        const float4 v4 = *(const float4*)(ee + d);
        const float va[4] = {v4.x, v4.y, v4.z, v4.w};
        #pragma unroll
        for (int k = 0; k < 4; ++k) {
            const float* qr = qt + (d + k) * B_ + b0;
            #pragma unroll
            for (int bb = 0; bb < BT; ++bb)
                acc[bb] = fmaf(va[k], qr[bb], acc[bb]);
        }
    }

    // ---- RBF score: acc[bb] += sum_l exp2(-(su[l][bb] - x[l]*r[l])^2) * wt[l][bb] ----
    const float* le = lit + (size_t)ec * L_;
    #pragma unroll 2
    for (int l = 0; l < L_; l += 4) {
        const float4 x4 = *(const float4*)(le + l);
        const float4 r4 = *(const float4*)(r + l);       // wave-uniform
        const float xa[4] = {x4.x, x4.y, x4.z, x4.w};
        const float ra[4] = {r4.x, r4.y, r4.z, r4.w};
        #pragma unroll
        for (int k = 0; k < 4; ++k) {
            const float u = xa[k] * ra[k];               // per-(e,l), amortized over BT
            const float* sr = su + (l + k) * B_ + b0;
            const float* wr = wt + (l + k) * B_ + b0;
            #pragma unroll
            for (int bb = 0; bb < BT; ++bb) {
                const float t  = sr[bb] - u;
                const float ph = __builtin_amdgcn_exp2f(t * (-t));
                acc[bb] = fmaf(ph, wr[bb], acc[bb]);
            }
        }
    }

    // ---- sigmoid + store (coalesced along e) ----
    if (e < E_) {
        #pragma unroll
        for (int bb = 0; bb < BT; ++bb) {
            const float z   = acc[bb];
            const float ezn = __builtin_amdgcn_exp2f(-z * LOG2E);
            out[(size_t)(b0 + bb) * E_ + e] = __builtin_amdgcn_rcpf(1.0f + ezn);
        }
    }
}

extern "C" void kernel_launch(void* const* d_in, const int* in_sizes, int n_in,
                              void* d_out, int out_size, void* d_ws, size_t ws_size,
                              hipStream_t stream) {
    const float* emb_e   = (const float*)d_in[0];
    const float* emb_rel = (const float*)d_in[1];
    const float* nfw     = (const float*)d_in[2];
    const float* lit     = (const float*)d_in[3];
    const float* c       = (const float*)d_in[4];
    const float* var     = (const float*)d_in[5];
    const int*   e1      = (const int*)d_in[6];
    const int*   rel     = (const int*)d_in[7];
    float* out = (float*)d_out;

    char* ws = (char*)d_ws;
    float* qt = (float*)(ws);                 // 200*256*4 = 204800 B
    float* su = (float*)(ws + 204800);        // 64*256*4  = 65536 B
    float* wt = (float*)(ws + 270336);        // 64*256*4  = 65536 B
    float* r  = (float*)(ws + 335872);        // 64*4      = 256 B

    setup_k<<<dim3(B_), dim3(256), 0, stream>>>(emb_e, emb_rel, nfw, lit, c, var,
                                                e1, rel, qt, su, wt, r);

    dim3 grid((E_ + 255) / 256, B_ / BT);
    main_k<<<grid, dim3(256), 0, stream>>>(emb_e, lit, qt, su, wt, r, out);
}

// Round 3
// 122.896 us; speedup vs baseline: 1.1350x; 1.1350x over previous
//
#include <hip/hip_runtime.h>

#define E_ 15000
#define D_ 200
#define L_ 64
#define B_ 256
#define BT 16
#define LOG2E 1.4426950408889634f

// ws layout:
//   qt  @ 0        : D_*B_ f32        (204800 B)   qt[d][b] = emb_e[e1[b],d]*emb_rel[rel[b],d]
//   swt @ 204800   : L_*B_ float2     (131072 B)   swt[l][b] = { (lit[e1,l]-c[l])*r[l], nfw[rel,l] }
//   r   @ 335872   : L_ f32           (256 B)      r[l] = sqrt(log2e/var[l])
//   p0  @ 1048576  : B_*E_ f32        (15.36 MB)   split-0 partial scores
//   p1  @ 16408576 : B_*E_ f32        (15.36 MB)   split-1 partial scores
#define QT_OFF   0
#define SWT_OFF  204800
#define R_OFF    335872
#define P0_OFF   1048576
#define P1_OFF   (P0_OFF + B_*E_*4)
#define WS_NEED  (P1_OFF + B_*E_*4)

__global__ __launch_bounds__(256) void setup_k(
    const float* __restrict__ emb_e, const float* __restrict__ emb_rel,
    const float* __restrict__ nfw,   const float* __restrict__ lit,
    const float* __restrict__ c,     const float* __restrict__ var,
    const int* __restrict__ e1,      const int* __restrict__ rel,
    float* __restrict__ qt, float2* __restrict__ swt, float* __restrict__ r)
{
    const int b = blockIdx.x;
    const int t = threadIdx.x;
    const int ie = e1[b];
    const int ir = rel[b];
    if (t < D_) qt[t * B_ + b] = emb_e[ie * D_ + t] * emb_rel[ir * D_ + t];
    if (t < L_) {
        const float rl = sqrtf(LOG2E / var[t]);
        swt[t * B_ + b] = make_float2((lit[ie * L_ + t] - c[t]) * rl,
                                      nfw[ir * L_ + t]);
        if (b == 0) r[t] = rl;
    }
}

// One split's worth of score: d in [DLO,DHI), l in [LLO,LHI).
// lane -> e (coalesced), BT b's per thread in registers.
template<int DLO, int DHI, int LLO, int LHI, bool FINAL>
__device__ __forceinline__ void body(
    const float* __restrict__ emb_e, const float* __restrict__ lit,
    const float* __restrict__ qt,    const float2* __restrict__ swt,
    const float* __restrict__ r,     float* __restrict__ dst)
{
    const int e  = blockIdx.x * 256 + threadIdx.x;
    const int ec = (e < E_) ? e : (E_ - 1);
    const int b0 = blockIdx.y * BT;

    float acc[BT];
    #pragma unroll
    for (int i = 0; i < BT; ++i) acc[i] = 0.0f;

    // ---- structural: acc[bb] += sum_{d in half} emb_e[ec,d] * qt[d][b0+bb] ----
    const float* ee = emb_e + (size_t)ec * D_;
    #pragma unroll 2
    for (int d = DLO; d < DHI; d += 4) {
        const float4 v4 = *(const float4*)(ee + d);
        const float va[4] = {v4.x, v4.y, v4.z, v4.w};
        #pragma unroll
        for (int k = 0; k < 4; ++k) {
            const float* qr = qt + (d + k) * B_ + b0;
            #pragma unroll
            for (int bb = 0; bb < BT; ++bb)
                acc[bb] = fmaf(va[k], qr[bb], acc[bb]);
        }
    }

    // ---- RBF: acc[bb] += sum_{l in half} exp2(-(su - x*r)^2) * wt ----
    const float* le = lit + (size_t)ec * L_;
    #pragma unroll 2
    for (int l = LLO; l < LHI; l += 4) {
        const float4 x4 = *(const float4*)(le + l);
        const float4 r4 = *(const float4*)(r + l);       // wave-uniform
        const float xa[4] = {x4.x, x4.y, x4.z, x4.w};
        const float ra[4] = {r4.x, r4.y, r4.z, r4.w};
        #pragma unroll
        for (int k = 0; k < 4; ++k) {
            const float u = xa[k] * ra[k];
            const float2* sw = swt + (l + k) * B_ + b0;  // wave-uniform rows
            #pragma unroll
            for (int bb = 0; bb < BT; ++bb) {
                const float2 s2 = sw[bb];
                const float t  = s2.x - u;
                const float ph = __builtin_amdgcn_exp2f(-t * t);
                acc[bb] = fmaf(ph, s2.y, acc[bb]);
            }
        }
    }

    if (e < E_) {
        #pragma unroll
        for (int bb = 0; bb < BT; ++bb) {
            float z = acc[bb];
            if (FINAL) {
                const float ezn = __builtin_amdgcn_exp2f(-z * LOG2E);
                z = __builtin_amdgcn_rcpf(1.0f + ezn);
            }
            dst[(size_t)(b0 + bb) * E_ + e] = z;
        }
    }
}

// Split-K main: gridDim.z == 2 selects the half (single launch so both halves
// run concurrently; two stream-ordered launches would serialize).
__global__ __launch_bounds__(256) void main_split_k(
    const float* __restrict__ emb_e, const float* __restrict__ lit,
    const float* __restrict__ qt,    const float2* __restrict__ swt,
    const float* __restrict__ r,     float* __restrict__ p0,
    float* __restrict__ p1)
{
    if (blockIdx.z == 0)
        body<0, 100, 0, 32, false>(emb_e, lit, qt, swt, r, p0);
    else
        body<100, 200, 32, 64, false>(emb_e, lit, qt, swt, r, p1);
}

// Fallback (ws too small): single-pass, writes sigmoid directly.
__global__ __launch_bounds__(256) void main_full_k(
    const float* __restrict__ emb_e, const float* __restrict__ lit,
    const float* __restrict__ qt,    const float2* __restrict__ swt,
    const float* __restrict__ r,     float* __restrict__ out)
{
    body<0, 200, 0, 64, true>(emb_e, lit, qt, swt, r, out);
}

// out = sigmoid(p0 + p1), float4-vectorized. B_*E_/4 = 960000 = 3750*256.
__global__ __launch_bounds__(256) void combine_k(
    const float4* __restrict__ p0, const float4* __restrict__ p1,
    float4* __restrict__ out)
{
    const int i = blockIdx.x * 256 + threadIdx.x;
    const float4 a = p0[i];
    const float4 b = p1[i];
    float4 o;
    o.x = __builtin_amdgcn_rcpf(1.0f + __builtin_amdgcn_exp2f(-(a.x + b.x) * LOG2E));
    o.y = __builtin_amdgcn_rcpf(1.0f + __builtin_amdgcn_exp2f(-(a.y + b.y) * LOG2E));
    o.z = __builtin_amdgcn_rcpf(1.0f + __builtin_amdgcn_exp2f(-(a.z + b.z) * LOG2E));
    o.w = __builtin_amdgcn_rcpf(1.0f + __builtin_amdgcn_exp2f(-(a.w + b.w) * LOG2E));
    out[i] = o;
}

extern "C" void kernel_launch(void* const* d_in, const int* in_sizes, int n_in,
                              void* d_out, int out_size, void* d_ws, size_t ws_size,
                              hipStream_t stream) {
    const float* emb_e   = (const float*)d_in[0];
    const float* emb_rel = (const float*)d_in[1];
    const float* nfw     = (const float*)d_in[2];
    const float* lit     = (const float*)d_in[3];
    const float* c       = (const float*)d_in[4];
    const float* var     = (const float*)d_in[5];
    const int*   e1      = (const int*)d_in[6];
    const int*   rel     = (const int*)d_in[7];
    float* out = (float*)d_out;

    char* ws = (char*)d_ws;
    float*  qt  = (float*)(ws + QT_OFF);
    float2* swt = (float2*)(ws + SWT_OFF);
    float*  r   = (float*)(ws + R_OFF);
    float*  p0  = (float*)(ws + P0_OFF);
    float*  p1  = (float*)(ws + P1_OFF);

    setup_k<<<dim3(B_), dim3(256), 0, stream>>>(emb_e, emb_rel, nfw, lit, c, var,
                                                e1, rel, qt, swt, r);

    if (ws_size >= (size_t)WS_NEED) {
        dim3 grid((E_ + 255) / 256, B_ / BT, 2);
        main_split_k<<<grid, dim3(256), 0, stream>>>(emb_e, lit, qt, swt, r, p0, p1);
        combine_k<<<dim3(B_ * E_ / 4 / 256), dim3(256), 0, stream>>>(
            (const float4*)p0, (const float4*)p1, (float4*)out);
    } else {
        dim3 grid((E_ + 255) / 256, B_ / BT, 1);
        main_full_k<<<grid, dim3(256), 0, stream>>>(emb_e, lit, qt, swt, r, out);
    }
}